// Round 8
// baseline (586.710 us; speedup 1.0000x reference)
//
#include <hip/hip_runtime.h>
#include <hip/hip_bf16.h>

#define B_ 4
#define N_ 1024
#define D_ 1024
#define H_ 16
#define DH_ 64
#define E_ 2112
#define ROWS_ 4096

typedef __bf16 bf16_t;
typedef bf16_t bf16x4 __attribute__((ext_vector_type(4)));
typedef bf16_t bf16x8 __attribute__((ext_vector_type(8)));
typedef float f32x4 __attribute__((ext_vector_type(4)));

__device__ __forceinline__ void gload_lds16(const void* g, void* l) {
  __builtin_amdgcn_global_load_lds(
      (const __attribute__((address_space(1))) void*)g,
      (__attribute__((address_space(3))) void*)l, 16, 0, 0);
}

// ---------------------------------------------------------------------------
// conversion passes (unchanged)
// ---------------------------------------------------------------------------
__global__ __launch_bounds__(256)
void conv_x(const float* __restrict__ x, bf16_t* __restrict__ xb) {
  const int n4 = ROWS_ * D_ / 4;
  for (int i = blockIdx.x * 256 + threadIdx.x; i < n4; i += gridDim.x * 256) {
    float4 v = ((const float4*)x)[i];
    bf16x4 o = {(bf16_t)v.x, (bf16_t)v.y, (bf16_t)v.z, (bf16_t)v.w};
    ((bf16x4*)xb)[i] = o;
  }
}

__global__ __launch_bounds__(256)
void conv_wkqv(const float* __restrict__ W, bf16_t* __restrict__ Wt, int h0) {
  const int et = blockIdx.x, dt = blockIdx.y, hz = blockIdx.z;
  const float* Wh = W + (size_t)(h0 + hz) * D_ * E_;
  __shared__ float tile[64][65];
  const int t = threadIdx.x;
  const int drow = t >> 4, e4 = (t & 15) * 4;
  #pragma unroll
  for (int i = 0; i < 4; ++i) {
    int d = dt * 64 + drow + i * 16;
    float4 v = *(const float4*)(Wh + (size_t)d * E_ + et * 64 + e4);
    tile[drow + i * 16][e4 + 0] = v.x;
    tile[drow + i * 16][e4 + 1] = v.y;
    tile[drow + i * 16][e4 + 2] = v.z;
    tile[drow + i * 16][e4 + 3] = v.w;
  }
  __syncthreads();
  const int erow = t >> 3, d8 = (t & 7) * 8;
  bf16_t* Wto = Wt + (size_t)hz * 2048 * D_;
  #pragma unroll
  for (int i = 0; i < 2; ++i) {
    int e = erow + i * 32;
    bf16x8 o;
    #pragma unroll
    for (int j = 0; j < 8; ++j) o[j] = (bf16_t)tile[d8 + j][e];
    *(bf16x8*)(Wto + (size_t)(et * 64 + e) * D_ + dt * 64 + d8) = o;
  }
}

__global__ __launch_bounds__(256)
void conv_wv(const float* __restrict__ W, bf16_t* __restrict__ Wvt) {
  const int et = blockIdx.x, dt = blockIdx.y, h = blockIdx.z;
  const int tx = threadIdx.x & 31, ty = threadIdx.x >> 5;
  __shared__ float tile[32][33];
  const float* Wh = W + (size_t)h * D_ * E_;
  #pragma unroll
  for (int rr = 0; rr < 4; ++rr) {
    int d = dt * 32 + rr * 8 + ty;
    int dh = et * 32 + tx;
    tile[rr * 8 + ty][tx] = Wh[(size_t)d * E_ + 2048 + dh];
  }
  __syncthreads();
  bf16_t* Wvo = Wvt + (size_t)h * DH_ * D_;
  #pragma unroll
  for (int rr = 0; rr < 4; ++rr) {
    int dh = et * 32 + rr * 8 + ty;
    int d = dt * 32 + tx;
    Wvo[(size_t)dh * D_ + d] = (bf16_t)tile[tx][rr * 8 + ty];
  }
}

__global__ __launch_bounds__(256)
void conv_wp(const float* __restrict__ Wp, bf16_t* __restrict__ Wpt) {
  const int nt = blockIdx.x, kt = blockIdx.y;
  const int tx = threadIdx.x & 31, ty = threadIdx.x >> 5;
  __shared__ float tile[32][33];
  #pragma unroll
  for (int rr = 0; rr < 4; ++rr)
    tile[rr * 8 + ty][tx] = Wp[(size_t)(kt * 32 + rr * 8 + ty) * D_ + nt * 32 + tx];
  __syncthreads();
  #pragma unroll
  for (int rr = 0; rr < 4; ++rr)
    Wpt[(size_t)(nt * 32 + rr * 8 + ty) * D_ + kt * 32 + tx] = (bf16_t)tile[tx][rr * 8 + ty];
}

// ---------------------------------------------------------------------------
// 256x256xK=1024 deep-pipelined core (T2+T3+T4+T5). 8 waves (2M x 4N), BK=64,
// 2 LDS dbufs each for A,B. A halves by mi-parity (p0/p1 read Ah0, p2/p3 Ah1);
// B halves by output-col (each wave reads its fixed half at p0 AND p1).
// Staging issue points (all race-free: each STG targets LDS whose readers
// finished before a barrier the stager already passed):
//   p0(k): Ah1(k+1)   [readers of Ah1(k-1) done at p3(k-1) barrier]
//   p2(k): Bh0,Bh1(k+2) [readers of B(k) done at p1(k) barrier]
//   p3(k): Ah0(k+2)   [readers of Ah0(k) done at p1(k) barrier]
// Covers: B 6-7 phases, Ah0 5, Ah1 6 (>= ~750 cy >= HBM latency).
// Counted waits (loads, 2 per STG item):
//   p1-end: protect Ah1(k) [issued p0(k-1)]; newer: B01(k+1)=4, Ah0(k+1)=2,
//           Ah1(k+1)=2 -> vmcnt(8)
//   p3-end: protect B01(k+1)+Ah0(k+1) for p0(k+1); newer: Ah1(k+1)=2,
//           B01(k+2)=4, Ah0(k+2)=2 -> vmcnt(8)
// Tail (skipped stages shrink queue -> must re-count): kt=14: W1=8, W3=2;
// kt=15: W1=0, W3=none. Main loop never drains to 0.
// ---------------------------------------------------------------------------
#define WV8 asm volatile("s_waitcnt vmcnt(8)" ::: "memory")
#define WV2 asm volatile("s_waitcnt vmcnt(2)" ::: "memory")
#define WV0 asm volatile("s_waitcnt vmcnt(0)" ::: "memory")
#define WNONE

__device__ __forceinline__ void mm256_core(const bf16_t* __restrict__ Ag,
                                           const bf16_t* __restrict__ Bg,
                                           bf16_t* lds, f32x4 (&acc)[8][4]) {
  char* Asp = (char*)lds;            // [2buf][2half][64 slots][128B]
  char* Bsp = (char*)lds + 65536;
  const int t = threadIdx.x;
  const int w = t >> 6, l = t & 63, l15 = l & 15, lg = l >> 4;
  const int wm = w >> 2, wn = w & 3;

  const int lr = l >> 3;
  const int scol = ((l & 7) ^ lr) << 3;         // pre-swizzled col (elems)
  const bf16_t* bS = Bg + (size_t)(w * 8 + lr) * 1024 + scol;
  const int idxA = w * 8 + lr;
  const bf16_t* aS0 = Ag + (size_t)((idxA >> 4) * 32 + (idxA & 15)) * 1024 + scol;
  const bf16_t* aS1 = aS0 + (size_t)128 * 1024;

#define STG_B(bufi, hh, ktv)                                                   \
  do {                                                                         \
    gload_lds16(bS + (size_t)((hh) * 128) * 1024 + (ktv) * 64,                 \
                Bsp + (bufi) * 32768 + (hh) * 16384 + w * 1024);               \
    gload_lds16(bS + (size_t)((hh) * 128 + 64) * 1024 + (ktv) * 64,            \
                Bsp + (bufi) * 32768 + (hh) * 16384 + 8192 + w * 1024);        \
  } while (0)
#define STG_A(bufi, hh, ktv)                                                   \
  do {                                                                         \
    gload_lds16(aS0 + (size_t)((hh) * 16) * 1024 + (ktv) * 64,                 \
                Asp + (bufi) * 32768 + (hh) * 16384 + w * 1024);               \
    gload_lds16(aS1 + (size_t)((hh) * 16) * 1024 + (ktv) * 64,                 \
                Asp + (bufi) * 32768 + (hh) * 16384 + 8192 + w * 1024);        \
  } while (0)

  // prologue: B0(0),B1(0),A0(0),A1(0),B0(1),B1(1),A0(1) = 14 loads;
  // need oldest 6 (B0(0),B1(0),A0(0)) -> vmcnt(8).
  STG_B(0, 0, 0); STG_B(0, 1, 0);
  STG_A(0, 0, 0); STG_A(0, 1, 0);
  STG_B(1, 0, 1); STG_B(1, 1, 1);
  STG_A(1, 0, 1);
  WV8;
  __builtin_amdgcn_s_barrier();

  const int rswz = (l15 & 7) << 4;
  const int bro = ((wn & 1) * 64 + l15) * 128;

#define TILE_STEP(KT, SA1, SB, SA0, W1, W3)                                    \
  {                                                                            \
    const int kb_ = (KT) & 1;                                                  \
    const char* Ab = Asp + kb_ * 32768;                                        \
    const char* Bb = Bsp + kb_ * 32768 + (wn >> 1) * 16384;                    \
    bf16x8 b0[4], b1[4];                                                       \
    { /* p0: B(ks0)+A-even(ks0); stage Ah1(KT+1) */                            \
      const int cs = (lg * 16) ^ rswz;                                         \
      bf16x8 a[4];                                                             \
      _Pragma("unroll") for (int ni = 0; ni < 4; ++ni)                         \
        b0[ni] = *(const bf16x8*)(Bb + bro + ni * 2048 + cs);                  \
      _Pragma("unroll") for (int q = 0; q < 4; ++q)                            \
        a[q] = *(const bf16x8*)(Ab + ((wm * 4 + q) * 16 + l15) * 128 + cs);    \
      if (SA1) STG_A(((KT) + 1) & 1, 1, (KT) + 1);                             \
      __builtin_amdgcn_s_barrier();                                            \
      asm volatile("s_waitcnt lgkmcnt(0)" ::: "memory");                       \
      __builtin_amdgcn_s_setprio(1);                                           \
      _Pragma("unroll") for (int q = 0; q < 4; ++q)                            \
        _Pragma("unroll") for (int ni = 0; ni < 4; ++ni)                       \
          acc[2 * q][ni] = __builtin_amdgcn_mfma_f32_16x16x32_bf16(            \
              a[q], b0[ni], acc[2 * q][ni], 0, 0, 0);                          \
      __builtin_amdgcn_s_setprio(0);                                           \
      __builtin_amdgcn_s_barrier();                                            \
    }                                                                          \
    { /* p1: B(ks1)+A-even(ks1) */                                             \
      const int cs = (64 + lg * 16) ^ rswz;                                    \
      bf16x8 a[4];                                                             \
      _Pragma("unroll") for (int ni = 0; ni < 4; ++ni)                         \
        b1[ni] = *(const bf16x8*)(Bb + bro + ni * 2048 + cs);                  \
      _Pragma("unroll") for (int q = 0; q < 4; ++q)                            \
        a[q] = *(const bf16x8*)(Ab + ((wm * 4 + q) * 16 + l15) * 128 + cs);    \
      __builtin_amdgcn_s_barrier();                                            \
      asm volatile("s_waitcnt lgkmcnt(0)" ::: "memory");                       \
      __builtin_amdgcn_s_setprio(1);                                           \
      _Pragma("unroll") for (int q = 0; q < 4; ++q)                            \
        _Pragma("unroll") for (int ni = 0; ni < 4; ++ni)                       \
          acc[2 * q][ni] = __builtin_amdgcn_mfma_f32_16x16x32_bf16(            \
              a[q], b1[ni], acc[2 * q][ni], 0, 0, 0);                          \
      __builtin_amdgcn_s_setprio(0);                                           \
      W1;                                                                      \
      __builtin_amdgcn_s_barrier();                                            \
    }                                                                          \
    { /* p2: A-odd(ks0); stage B01(KT+2) */                                    \
      const int cs = (lg * 16) ^ rswz;                                         \
      bf16x8 a[4];                                                             \
      _Pragma("unroll") for (int q = 0; q < 4; ++q)                            \
        a[q] = *(const bf16x8*)(Ab + 16384 + ((wm * 4 + q) * 16 + l15) * 128 + cs); \
      if (SB) { STG_B((KT) & 1, 0, (KT) + 2); STG_B((KT) & 1, 1, (KT) + 2); }  \
      __builtin_amdgcn_s_barrier();                                            \
      asm volatile("s_waitcnt lgkmcnt(0)" ::: "memory");                       \
      __builtin_amdgcn_s_setprio(1);                                           \
      _Pragma("unroll") for (int q = 0; q < 4; ++q)                            \
        _Pragma("unroll") for (int ni = 0; ni < 4; ++ni)                       \
          acc[2 * q + 1][ni] = __builtin_amdgcn_mfma_f32_16x16x32_bf16(        \
              a[q], b0[ni], acc[2 * q + 1][ni], 0, 0, 0);                      \
      __builtin_amdgcn_s_setprio(0);                                           \
      __builtin_amdgcn_s_barrier();                                            \
    }                                                                          \
    { /* p3: A-odd(ks1); stage Ah0(KT+2) */                                    \
      const int cs = (64 + lg * 16) ^ rswz;                                    \
      bf16x8 a[4];                                                             \
      _Pragma("unroll") for (int q = 0; q < 4; ++q)                            \
        a[q] = *(const bf16x8*)(Ab + 16384 + ((wm * 4 + q) * 16 + l15) * 128 + cs); \
      if (SA0) STG_A((KT) & 1, 0, (KT) + 2);                                   \
      __builtin_amdgcn_s_barrier();                                            \
      asm volatile("s_waitcnt lgkmcnt(0)" ::: "memory");                       \
      __builtin_amdgcn_s_setprio(1);                                           \
      _Pragma("unroll") for (int q = 0; q < 4; ++q)                            \
        _Pragma("unroll") for (int ni = 0; ni < 4; ++ni)                       \
          acc[2 * q + 1][ni] = __builtin_amdgcn_mfma_f32_16x16x32_bf16(        \
              a[q], b1[ni], acc[2 * q + 1][ni], 0, 0, 0);                      \
      __builtin_amdgcn_s_setprio(0);                                           \
      W3;                                                                      \
      __builtin_amdgcn_s_barrier();                                            \
    }                                                                          \
  }

  for (int kt = 0; kt < 14; ++kt) TILE_STEP(kt, 1, 1, 1, WV8, WV8);
  TILE_STEP(14, 1, 0, 0, WV8, WV2);
  TILE_STEP(15, 0, 0, 0, WV0, WNONE);

#undef TILE_STEP
#undef STG_A
#undef STG_B
}

// chunk-XOR for the epilogue transpose: 16B chunk c -> c ^ (c>>3), bijective.
__device__ __forceinline__ int xchunk4(int colf) {
  int c = colf >> 2;
  return ((c ^ (c >> 3)) << 2) | (colf & 3);
}

// ---------------------------------------------------------------------------
// Phase 1: [K|Q] = x @ Wkqv[h][:, :2048] + b for 8 heads. 256^2 core.
// ---------------------------------------------------------------------------
__global__ __launch_bounds__(512)
void kqv256(const bf16_t* __restrict__ xb, const bf16_t* __restrict__ Wt,
            const float* __restrict__ bkqv, int h0,
            bf16_t* __restrict__ Kc, bf16_t* __restrict__ Qc) {
  __shared__ bf16_t lds[65536];
  const int bid = blockIdx.x;
  const int lid = (bid & 7) * 128 + (bid >> 3);
  const int mb = lid & 15, nb = (lid >> 4) & 7, hz = lid >> 7;

  f32x4 acc[8][4] = {};
  mm256_core(xb + (size_t)mb * 256 * D_,
             Wt + ((size_t)hz * 2048 + (size_t)nb * 256) * D_, lds, acc);

  const int t = threadIdx.x;
  const int w = t >> 6, l = t & 63, l15 = l & 15, lg = l >> 4;
  const int wm = w >> 2, wn = w & 3;
  const int h = h0 + hz;

  float bias[4];
  #pragma unroll
  for (int ni = 0; ni < 4; ++ni)
    bias[ni] = bkqv[h * E_ + nb * 256 + wn * 64 + ni * 16 + l15];
  #pragma unroll
  for (int mi = 0; mi < 8; ++mi)
    #pragma unroll
    for (int ni = 0; ni < 4; ++ni)
      #pragma unroll
      for (int r = 0; r < 4; ++r) acc[mi][ni][r] += bias[ni];

  float* Ct = (float*)lds;   // [64][258], cols chunk-XOR swizzled
  const int cpair = t & 31;
  const int p0 = xchunk4(cpair * 8);
  const int p1 = xchunk4(cpair * 8 + 4);
  #pragma unroll
  for (int s = 0; s < 4; ++s) {
    __syncthreads();
    #pragma unroll
    for (int m2 = 0; m2 < 2; ++m2)
      #pragma unroll
      for (int ni = 0; ni < 4; ++ni)
        #pragma unroll
        for (int r = 0; r < 4; ++r)
          Ct[(wm * 32 + m2 * 16 + lg * 4 + r) * 258 +
             xchunk4(wn * 64 + ni * 16 + l15)] = acc[2 * s + m2][ni][r];
    __syncthreads();
    #pragma unroll
    for (int it = 0; it < 4; ++it) {
      int row64 = (t >> 5) + it * 16;
      int wmq = row64 >> 5, m2q = (row64 >> 4) & 1, r16 = row64 & 15;
      int c8 = cpair * 8;
      const float* r0 = &Ct[row64 * 258 + p0];
      const float* r1 = &Ct[row64 * 258 + p1];
      bf16x8 o = {(bf16_t)r0[0], (bf16_t)r0[1], (bf16_t)r0[2], (bf16_t)r0[3],
                  (bf16_t)r1[0], (bf16_t)r1[1], (bf16_t)r1[2], (bf16_t)r1[3]};
      int grow = mb * 256 + wmq * 128 + (2 * s + m2q) * 16 + r16;
      int b = grow >> 10, n = grow & (N_ - 1);
      int bhl = b * 8 + hz;
      size_t base = ((size_t)bhl * N_ + n) * D_;
      if (nb < 4)
        *(bf16x8*)(Kc + base + nb * 256 + c8) = o;
      else
        *(bf16x8*)(Qc + base + nb * 256 - 1024 + c8) = o;
    }
  }
}

// ---------------------------------------------------------------------------
// Phase 2a: S = scale * Q.K^T, lower-triangle 256x256 tiles (10 per bh).
// ---------------------------------------------------------------------------
__global__ __launch_bounds__(512)
void s_gemm256(const bf16_t* __restrict__ Qc, const bf16_t* __restrict__ Kc,
               float* __restrict__ SgC) {
  __shared__ bf16_t lds[65536];
  const int bid = blockIdx.x;
  const int lid = (bid & 7) * 40 + (bid >> 3);
  const int idx = lid % 10;
  const int bhl = lid / 10;
  int qt = 0;
  while ((qt + 1) * (qt + 2) / 2 <= idx) ++qt;
  const int kt = idx - qt * (qt + 1) / 2;

  f32x4 acc[8][4] = {};
  mm256_core(Qc + ((size_t)bhl * N_ + (size_t)qt * 256) * D_,
             Kc + ((size_t)bhl * N_ + (size_t)kt * 256) * D_, lds, acc);

  const int t = threadIdx.x;
  const int w = t >> 6, l = t & 63, l15 = l & 15, lg = l >> 4;
  const int wm = w >> 2, wn = w & 3;
  const float SCALE = 0.045084220027780106f;   // log2(e)/sqrt(1024)
  float* So = SgC + (((size_t)bhl * 10 + idx) << 16);

  #pragma unroll
  for (int mi = 0; mi < 8; ++mi)
    #pragma unroll
    for (int ni = 0; ni < 4; ++ni)
      #pragma unroll
      for (int r = 0; r < 4; ++r) {
        int rl = wm * 128 + mi * 16 + lg * 4 + r;
        int cl = wn * 64 + ni * 16 + l15;
        float z = acc[mi][ni][r] * SCALE;
        if (kt * 256 + cl > qt * 256 + rl) z = -1e30f;
        acc[mi][ni][r] = z;
      }

  float* Ct = (float*)lds;
  const int cpair = t & 31;
  const int p0 = xchunk4(cpair * 8);
  const int p1 = xchunk4(cpair * 8 + 4);
  #pragma unroll
  for (int s = 0; s < 4; ++s) {
    __syncthreads();
    #pragma unroll
    for (int m2 = 0; m2 < 2; ++m2)
      #pragma unroll
      for (int ni = 0; ni < 4; ++ni)
        #pragma unroll
        for (int r = 0; r < 4; ++r)
          Ct[(wm * 32 + m2 * 16 + lg * 4 + r) * 258 +
             xchunk4(wn * 64 + ni * 16 + l15)] = acc[2 * s + m2][ni][r];
    __syncthreads();
    #pragma unroll
    for (int it = 0; it < 4; ++it) {
      int row64 = (t >> 5) + it * 16;
      int wmq = row64 >> 5, m2q = (row64 >> 4) & 1, r16 = row64 & 15;
      int c8 = cpair * 8;
      const float* r0 = &Ct[row64 * 258 + p0];
      const float* r1 = &Ct[row64 * 258 + p1];
      float4 v0 = {r0[0], r0[1], r0[2], r0[3]};
      float4 v1 = {r1[0], r1[1], r1[2], r1[3]};
      int rl = wmq * 128 + (2 * s + m2q) * 16 + r16;
      *(float4*)(So + (size_t)rl * 256 + c8) = v0;
      *(float4*)(So + (size_t)rl * 256 + c8 + 4) = v1;
    }
  }
}

// ---------------------------------------------------------------------------
// V gemm (unchanged)
// ---------------------------------------------------------------------------
__global__ __launch_bounds__(256)
void v_gemm(const bf16_t* __restrict__ xb, const bf16_t* __restrict__ Wvt,
            const float* __restrict__ bkqv, bf16_t* __restrict__ Vt) {
  const int nt = blockIdx.x;
  const int h = blockIdx.y;
  const int t = threadIdx.x;
  const int w = t >> 6, l = t & 63, l15 = l & 15, lg = l >> 4;

  __shared__ bf16_t As2[64 * 64];
  __shared__ bf16_t Bs2[128 * 64];
  const bf16_t* Wvh = Wvt + (size_t)h * DH_ * D_;
  const bf16_t* Bn = xb + (size_t)nt * 128 * D_;

  f32x4 acc[4][2] = {};
  const int rswz = (l15 & 7) << 4;

  for (int kb = 0; kb < 16; ++kb) {
    __syncthreads();
    #pragma unroll
    for (int i = 0; i < 2; ++i) {
      int idx = t + i * 256;
      int row = idx >> 3, c = idx & 7;
      gload_lds16(Wvh + (size_t)row * D_ + kb * 64 + ((c ^ (row & 7)) << 3),
                  (char*)As2 + idx * 16);
    }
    #pragma unroll
    for (int i = 0; i < 4; ++i) {
      int idx = t + i * 256;
      int row = idx >> 3, c = idx & 7;
      gload_lds16(Bn + (size_t)row * D_ + kb * 64 + ((c ^ (row & 7)) << 3),
                  (char*)Bs2 + idx * 16);
    }
    __syncthreads();
    #pragma unroll
    for (int ks = 0; ks < 2; ++ks) {
      const int cswz = (ks * 64 + lg * 16) ^ rswz;
      bf16x8 a[4], b[2];
      #pragma unroll
      for (int mi = 0; mi < 4; ++mi)
        a[mi] = *(const bf16x8*)((const char*)As2 + (mi * 16 + l15) * 128 + cswz);
      #pragma unroll
      for (int ni = 0; ni < 2; ++ni)
        b[ni] = *(const bf16x8*)((const char*)Bs2 + (w * 32 + ni * 16 + l15) * 128 + cswz);
      #pragma unroll
      for (int mi = 0; mi < 4; ++mi)
        #pragma unroll
        for (int ni = 0; ni < 2; ++ni)
          acc[mi][ni] = __builtin_amdgcn_mfma_f32_16x16x32_bf16(a[mi], b[ni], acc[mi][ni], 0, 0, 0);
    }
  }

  #pragma unroll
  for (int mi = 0; mi < 4; ++mi)
    #pragma unroll
    for (int r = 0; r < 4; ++r) {
      int dh = mi * 16 + lg * 4 + r;
      float bias = bkqv[h * E_ + 2048 + dh];
      #pragma unroll
      for (int ni = 0; ni < 2; ++ni) {
        int nn = nt * 128 + w * 32 + ni * 16 + l15;
        int b = nn >> 10, n = nn & (N_ - 1);
        int bh = b * H_ + h;
        Vt[((size_t)bh * DH_ + dh) * N_ + n] = (bf16_t)(acc[mi][ni][r] + bias);
      }
    }
}

// ---------------------------------------------------------------------------
// Phase 2b: softmax + P.V (unchanged)
// ---------------------------------------------------------------------------
__global__ __launch_bounds__(256)
void softmax_pv(const float* __restrict__ SgC, const bf16_t* __restrict__ Vt,
                bf16_t* __restrict__ sa, int c) {
  const int qt = blockIdx.x;
  const int bhl = blockIdx.y;
  const int t = threadIdx.x;
  const int w = t >> 6, l = t & 63, l15 = l & 15, lg = l >> 4;
  const int b = bhl >> 3, h = c * 8 + (bhl & 7);
  const int bh = b * H_ + h;

  const int qrow = qt * 64 + w * 16 + l15;
  const int qt8 = qt >> 2;
  const float* Sbh = SgC + (((size_t)bhl * 10) << 16);
  const bf16_t* Vh = Vt + (size_t)bh * DH_ * N_;

  f32x4 accO[4] = {};
  float m = -1e30f, lsum = 0.f;

  for (int j = 0; j <= qt; ++j) {
    const int jb = j * 64;
    const int tid = qt8 * (qt8 + 1) / 2 + (j >> 2);
    const float* Srow = Sbh + ((size_t)tid << 16) + (size_t)(qrow & 255) * 256 + (jb & 255);

    float4 sA = *(const float4*)(Srow + lg * 8);
    float4 sB = *(const float4*)(Srow + lg * 8 + 4);
    float4 sC = *(const float4*)(Srow + 32 + lg * 8);
    float4 sD = *(const float4*)(Srow + 32 + lg * 8 + 4);

    float zm = fmaxf(fmaxf(fmaxf(sA.x, sA.y), fmaxf(sA.z, sA.w)),
                     fmaxf(fmaxf(sB.x, sB.y), fmaxf(sB.z, sB.w)));
    zm = fmaxf(zm, fmaxf(fmaxf(fmaxf(sC.x, sC.y), fmaxf(sC.z, sC.w)),
                         fmaxf(fmaxf(sD.x, sD.y), fmaxf(sD.z, sD.w))));
    zm = fmaxf(zm, __shfl_xor(zm, 16));
    zm = fmaxf(zm, __shfl_xor(zm, 32));

    float mnew = fmaxf(m, zm);
    float scl = exp2f(m - mnew);
    m = mnew;

    float p[16];
    p[0] = exp2f(sA.x - mnew); p[1] = exp2f(sA.y - mnew);
    p[2] = exp2f(sA.z - mnew); p[3] = exp2f(sA.w - mnew);
    p[4] = exp2f(sB.x - mnew); p[5] = exp2f(sB.y - mnew);
    p[6] = exp2f(sB.z - mnew); p[7] = exp2f(sB.w - mnew);
    p[8] = exp2f(sC.x - mnew); p[9] = exp2f(sC.y - mnew);
    p[10] = exp2f(sC.z - mnew); p[11] = exp2f(sC.w - mnew);
    p[12] = exp2f(sD.x - mnew); p[13] = exp2f(sD.y - mnew);
    p[14] = exp2f(sD.z - mnew); p[15] = exp2f(sD.w - mnew);

    float rs = 0.f;
    #pragma unroll
    for (int i = 0; i < 16; ++i) rs += p[i];
    rs += __shfl_xor(rs, 16);
    rs += __shfl_xor(rs, 32);
    lsum = lsum * scl + rs;

    float sclO[4];
    #pragma unroll
    for (int r = 0; r < 4; ++r) sclO[r] = __shfl(scl, lg * 4 + r);
    #pragma unroll
    for (int db = 0; db < 4; ++db)
      #pragma unroll
      for (int r = 0; r < 4; ++r) accO[db][r] *= sclO[r];

    bf16x8 pa0 = {(bf16_t)p[0], (bf16_t)p[1], (bf16_t)p[2], (bf16_t)p[3],
                  (bf16_t)p[4], (bf16_t)p[5], (bf16_t)p[6], (bf16_t)p[7]};
    bf16x8 pa1 = {(bf16_t)p[8], (bf16_t)p[9], (bf16_t)p[10], (bf16_t)p[11],
                  (bf16_t)p[12], (bf16_t)p[13], (bf16_t)p[14], (bf16_t)p[15]};

    #pragma unroll
    for (int db = 0; db < 4; ++db) {
      const bf16_t* vp = Vh + (size_t)(db * 16 + l15) * N_ + jb;
      bf16x8 vb0 = *(const bf16x8*)(vp + lg * 8);
      bf16x8 vb1 = *(const bf16x8*)(vp + 32 + lg * 8);
      accO[db] = __builtin_amdgcn_mfma_f32_16x16x32_bf16(pa0, vb0, accO[db], 0, 0, 0);
      accO[db] = __builtin_amdgcn_mfma_f32_16x16x32_bf16(pa1, vb1, accO[db], 0, 0, 0);
    }
  }

  float lO[4];
  #pragma unroll
  for (int r = 0; r < 4; ++r) lO[r] = __shfl(lsum, lg * 4 + r);

  #pragma unroll
  for (int db = 0; db < 4; ++db)
    #pragma unroll
    for (int r = 0; r < 4; ++r) {
      int row = qt * 64 + w * 16 + lg * 4 + r;
      int col = h * DH_ + db * 16 + l15;
      sa[((size_t)b * N_ + row) * D_ + col] = (bf16_t)(accO[db][r] / lO[r]);
    }
}

// ---------------------------------------------------------------------------
// Phase 3: out = sa @ Wp + bp (m97 128^2 structure, fp32 out)
// ---------------------------------------------------------------------------
__global__ __launch_bounds__(256)
void out_gemm(const bf16_t* __restrict__ A, const bf16_t* __restrict__ Bt,
              const float* __restrict__ bp, float* __restrict__ out) {
  const int mb = blockIdx.x, nb = blockIdx.y;
  const int t = threadIdx.x;
  const int w = t >> 6, l = t & 63, l15 = l & 15, lg = l >> 4;
  const int wr = (w >> 1) * 64, wc = (w & 1) * 64;

  __shared__ bf16_t As[128 * 64];
  __shared__ bf16_t Bs[128 * 64];

  const int srow = w * 32 + (l >> 3);
  const int scol = (l & 7) * 8;
  const bf16_t* ag = A + (size_t)(mb * 128 + srow) * D_ + scol;
  const bf16_t* bg = Bt + (size_t)(nb * 128 + srow) * D_ + scol;
  char* asl = (char*)As + w * 4096;
  char* bsl = (char*)Bs + w * 4096;

  f32x4 acc[4][4] = {};

  for (int kb = 0; kb < 16; ++kb) {
    __syncthreads();
    #pragma unroll
    for (int i = 0; i < 4; ++i) {
      gload_lds16(ag + (size_t)i * 8 * D_ + kb * 64, asl + i * 1024);
      gload_lds16(bg + (size_t)i * 8 * D_ + kb * 64, bsl + i * 1024);
    }
    __syncthreads();
    #pragma unroll
    for (int ks = 0; ks < 2; ++ks) {
      bf16x8 a[4], b[4];
      #pragma unroll
      for (int mi = 0; mi < 4; ++mi)
        a[mi] = *(const bf16x8*)((const char*)As + (wr + mi * 16 + l15) * 128 + ks * 64 + lg * 16);
      #pragma unroll
      for (int ni = 0; ni < 4; ++ni)
        b[ni] = *(const bf16x8*)((const char*)Bs + (wc + ni * 16 + l15) * 128 + ks * 64 + lg * 16);
      #pragma unroll
      for (int mi = 0; mi < 4; ++mi)
        #pragma unroll
        for (int ni = 0; ni < 4; ++ni)
          acc[mi][ni] = __builtin_amdgcn_mfma_f32_16x16x32_bf16(a[mi], b[ni], acc[mi][ni], 0, 0, 0);
    }
  }

  #pragma unroll
  for (int ni = 0; ni < 4; ++ni) {
    int e = nb * 128 + wc + ni * 16 + l15;
    float bias = bp[e];
    #pragma unroll
    for (int mi = 0; mi < 4; ++mi)
      #pragma unroll
      for (int r = 0; r < 4; ++r) {
        int grow = mb * 128 + wr + mi * 16 + lg * 4 + r;
        out[(size_t)grow * D_ + e] = acc[mi][ni][r] + bias;
      }
  }
}

// ---------------------------------------------------------------------------
extern "C" void kernel_launch(void* const* d_in, const int* in_sizes, int n_in,
                              void* d_out, int out_size, void* d_ws, size_t ws_size,
                              hipStream_t stream) {
  const float* x    = (const float*)d_in[0];
  const float* Wkqv = (const float*)d_in[1];
  const float* bkqv = (const float*)d_in[2];
  const float* Wp   = (const float*)d_in[3];
  const float* bp   = (const float*)d_in[4];
  float* out = (float*)d_out;
  char* ws = (char*)d_ws;

  const size_t MB = 1 << 20;
  bf16_t* xb  = (bf16_t*)(ws);             //   8 MiB
  bf16_t* sa  = (bf16_t*)(ws + 8 * MB);    //   8 MiB
  bf16_t* Wpt = (bf16_t*)(ws + 16 * MB);   //   2 MiB
  bf16_t* Vt  = (bf16_t*)(ws + 18 * MB);   //   8 MiB
  bf16_t* Qc  = (bf16_t*)(ws + 26 * MB);   //  64 MiB (32 bh)
  bf16_t* Kc  = (bf16_t*)(ws + 90 * MB);   //  64 MiB (32 bh)
  bf16_t* Wt  = (bf16_t*)(ws + 154 * MB);  //  32 MiB (8 heads)
  bf16_t* Wvt = (bf16_t*)(ws + 186 * MB);  //   2 MiB
  float*  SgC = (float*) (ws + 188 * MB);  //  80 MiB
  // total 268 MiB (< proven-safe 285,212,672 B)

  hipLaunchKernelGGL(conv_x, dim3(1024), dim3(256), 0, stream, x, xb);
  hipLaunchKernelGGL(conv_wp, dim3(32, 32), dim3(256), 0, stream, Wp, Wpt);
  hipLaunchKernelGGL(conv_wv, dim3(2, 32, 16), dim3(256), 0, stream, Wkqv, Wvt);
  hipLaunchKernelGGL(v_gemm, dim3(32, 16), dim3(256), 0, stream, xb, Wvt, bkqv, Vt);

  for (int c = 0; c < 2; ++c) {
    hipLaunchKernelGGL(conv_wkqv, dim3(32, 16, 8), dim3(256), 0, stream,
                       Wkqv, Wt, c * 8);
    hipLaunchKernelGGL(kqv256, dim3(1024), dim3(512), 0, stream,
                       xb, Wt, bkqv, c * 8, Kc, Qc);
    hipLaunchKernelGGL(s_gemm256, dim3(320), dim3(512), 0, stream,
                       Qc, Kc, SgC);
    hipLaunchKernelGGL(softmax_pv, dim3(16, 32), dim3(256), 0, stream,
                       SgC, Vt, sa, c);
  }

  hipLaunchKernelGGL(out_gemm, dim3(32, 8), dim3(256), 0, stream, sa, Wpt, bp, out);
}

// Round 9
// 577.125 us; speedup vs baseline: 1.0166x; 1.0166x over previous
//
#include <hip/hip_runtime.h>
#include <hip/hip_bf16.h>

#define B_ 4
#define N_ 1024
#define D_ 1024
#define H_ 16
#define DH_ 64
#define E_ 2112
#define ROWS_ 4096

typedef __bf16 bf16_t;
typedef bf16_t bf16x4 __attribute__((ext_vector_type(4)));
typedef bf16_t bf16x8 __attribute__((ext_vector_type(8)));
typedef float f32x4 __attribute__((ext_vector_type(4)));

__device__ __forceinline__ void gload_lds16(const void* g, void* l) {
  __builtin_amdgcn_global_load_lds(
      (const __attribute__((address_space(1))) void*)g,
      (__attribute__((address_space(3))) void*)l, 16, 0, 0);
}

// ---------------------------------------------------------------------------
// conversion passes (unchanged)
// ---------------------------------------------------------------------------
__global__ __launch_bounds__(256)
void conv_x(const float* __restrict__ x, bf16_t* __restrict__ xb) {
  const int n4 = ROWS_ * D_ / 4;
  for (int i = blockIdx.x * 256 + threadIdx.x; i < n4; i += gridDim.x * 256) {
    float4 v = ((const float4*)x)[i];
    bf16x4 o = {(bf16_t)v.x, (bf16_t)v.y, (bf16_t)v.z, (bf16_t)v.w};
    ((bf16x4*)xb)[i] = o;
  }
}

__global__ __launch_bounds__(256)
void conv_wkqv(const float* __restrict__ W, bf16_t* __restrict__ Wt, int h0) {
  const int et = blockIdx.x, dt = blockIdx.y, hz = blockIdx.z;
  const float* Wh = W + (size_t)(h0 + hz) * D_ * E_;
  __shared__ float tile[64][65];
  const int t = threadIdx.x;
  const int drow = t >> 4, e4 = (t & 15) * 4;
  #pragma unroll
  for (int i = 0; i < 4; ++i) {
    int d = dt * 64 + drow + i * 16;
    float4 v = *(const float4*)(Wh + (size_t)d * E_ + et * 64 + e4);
    tile[drow + i * 16][e4 + 0] = v.x;
    tile[drow + i * 16][e4 + 1] = v.y;
    tile[drow + i * 16][e4 + 2] = v.z;
    tile[drow + i * 16][e4 + 3] = v.w;
  }
  __syncthreads();
  const int erow = t >> 3, d8 = (t & 7) * 8;
  bf16_t* Wto = Wt + (size_t)hz * 2048 * D_;
  #pragma unroll
  for (int i = 0; i < 2; ++i) {
    int e = erow + i * 32;
    bf16x8 o;
    #pragma unroll
    for (int j = 0; j < 8; ++j) o[j] = (bf16_t)tile[d8 + j][e];
    *(bf16x8*)(Wto + (size_t)(et * 64 + e) * D_ + dt * 64 + d8) = o;
  }
}

__global__ __launch_bounds__(256)
void conv_wv(const float* __restrict__ W, bf16_t* __restrict__ Wvt) {
  const int et = blockIdx.x, dt = blockIdx.y, h = blockIdx.z;
  const int tx = threadIdx.x & 31, ty = threadIdx.x >> 5;
  __shared__ float tile[32][33];
  const float* Wh = W + (size_t)h * D_ * E_;
  #pragma unroll
  for (int rr = 0; rr < 4; ++rr) {
    int d = dt * 32 + rr * 8 + ty;
    int dh = et * 32 + tx;
    tile[rr * 8 + ty][tx] = Wh[(size_t)d * E_ + 2048 + dh];
  }
  __syncthreads();
  bf16_t* Wvo = Wvt + (size_t)h * DH_ * D_;
  #pragma unroll
  for (int rr = 0; rr < 4; ++rr) {
    int dh = et * 32 + rr * 8 + ty;
    int d = dt * 32 + tx;
    Wvo[(size_t)dh * D_ + d] = (bf16_t)tile[tx][rr * 8 + ty];
  }
}

__global__ __launch_bounds__(256)
void conv_wp(const float* __restrict__ Wp, bf16_t* __restrict__ Wpt) {
  const int nt = blockIdx.x, kt = blockIdx.y;
  const int tx = threadIdx.x & 31, ty = threadIdx.x >> 5;
  __shared__ float tile[32][33];
  #pragma unroll
  for (int rr = 0; rr < 4; ++rr)
    tile[rr * 8 + ty][tx] = Wp[(size_t)(kt * 32 + rr * 8 + ty) * D_ + nt * 32 + tx];
  __syncthreads();
  #pragma unroll
  for (int rr = 0; rr < 4; ++rr)
    Wpt[(size_t)(nt * 32 + rr * 8 + ty) * D_ + kt * 32 + tx] = (bf16_t)tile[tx][rr * 8 + ty];
}

// ---------------------------------------------------------------------------
// 256x256xK=1024 deep-pipelined core. ONE barrier per phase (at phase end,
// after the counted vmcnt). The pre-MFMA barrier is removed: lgkmcnt(0)
// covers own-wave ds_reads; staging-vs-reader races are excluded because
// with 1 barrier/phase the skew is <1 phase and every STG target's readers
// ran lgkmcnt(0) >= 2 phase-barriers before the STG issue point:
//   p0(k) stages Ah1(k+1): readers (p2/p3 of k-1) drained by p3(k-1) barrier.
//   p2(k) stages B01(k+2): readers (p0/p1 of k) drained by p1(k) barrier.
//   p3(k) stages Ah0(k+2): readers (p0/p1 of k) drained by p1(k) barrier.
// vmcnt publication: counted wait + phase-end barrier (counts unchanged):
//   p1-end vmcnt(8) completes Ah1(k); p3-end vmcnt(8) completes B01(k+1)+
//   Ah0(k+1). Tail: kt=14 -> (8,2); kt=15 -> (0,none).
// ---------------------------------------------------------------------------
#define WV8 asm volatile("s_waitcnt vmcnt(8)" ::: "memory")
#define WV2 asm volatile("s_waitcnt vmcnt(2)" ::: "memory")
#define WV0 asm volatile("s_waitcnt vmcnt(0)" ::: "memory")
#define WNONE

__device__ __forceinline__ void mm256_core(const bf16_t* __restrict__ Ag,
                                           const bf16_t* __restrict__ Bg,
                                           bf16_t* lds, f32x4 (&acc)[8][4]) {
  char* Asp = (char*)lds;            // [2buf][2half][64 slots][128B]
  char* Bsp = (char*)lds + 65536;
  const int t = threadIdx.x;
  const int w = t >> 6, l = t & 63, l15 = l & 15, lg = l >> 4;
  const int wm = w >> 2, wn = w & 3;

  const int lr = l >> 3;
  const int scol = ((l & 7) ^ lr) << 3;         // pre-swizzled col (elems)
  const bf16_t* bS = Bg + (size_t)(w * 8 + lr) * 1024 + scol;
  const int idxA = w * 8 + lr;
  const bf16_t* aS0 = Ag + (size_t)((idxA >> 4) * 32 + (idxA & 15)) * 1024 + scol;
  const bf16_t* aS1 = aS0 + (size_t)128 * 1024;

#define STG_B(bufi, hh, ktv)                                                   \
  do {                                                                         \
    gload_lds16(bS + (size_t)((hh) * 128) * 1024 + (ktv) * 64,                 \
                Bsp + (bufi) * 32768 + (hh) * 16384 + w * 1024);               \
    gload_lds16(bS + (size_t)((hh) * 128 + 64) * 1024 + (ktv) * 64,            \
                Bsp + (bufi) * 32768 + (hh) * 16384 + 8192 + w * 1024);        \
  } while (0)
#define STG_A(bufi, hh, ktv)                                                   \
  do {                                                                         \
    gload_lds16(aS0 + (size_t)((hh) * 16) * 1024 + (ktv) * 64,                 \
                Asp + (bufi) * 32768 + (hh) * 16384 + w * 1024);               \
    gload_lds16(aS1 + (size_t)((hh) * 16) * 1024 + (ktv) * 64,                 \
                Asp + (bufi) * 32768 + (hh) * 16384 + 8192 + w * 1024);        \
  } while (0)

  // prologue: B0(0),B1(0),A0(0),A1(0),B0(1),B1(1),A0(1) = 14 loads;
  // need oldest 6 (B0(0),B1(0),A0(0)) -> vmcnt(8).
  STG_B(0, 0, 0); STG_B(0, 1, 0);
  STG_A(0, 0, 0); STG_A(0, 1, 0);
  STG_B(1, 0, 1); STG_B(1, 1, 1);
  STG_A(1, 0, 1);
  WV8;
  __builtin_amdgcn_s_barrier();

  const int rswz = (l15 & 7) << 4;
  const int bro = ((wn & 1) * 64 + l15) * 128;

#define TILE_STEP(KT, SA1, SB, SA0, W1, W3)                                    \
  {                                                                            \
    const int kb_ = (KT) & 1;                                                  \
    const char* Ab = Asp + kb_ * 32768;                                        \
    const char* Bb = Bsp + kb_ * 32768 + (wn >> 1) * 16384;                    \
    bf16x8 b0[4], b1[4];                                                       \
    { /* p0: B(ks0)+A-even(ks0); stage Ah1(KT+1) */                            \
      const int cs = (lg * 16) ^ rswz;                                         \
      bf16x8 a[4];                                                             \
      _Pragma("unroll") for (int ni = 0; ni < 4; ++ni)                         \
        b0[ni] = *(const bf16x8*)(Bb + bro + ni * 2048 + cs);                  \
      _Pragma("unroll") for (int q = 0; q < 4; ++q)                            \
        a[q] = *(const bf16x8*)(Ab + ((wm * 4 + q) * 16 + l15) * 128 + cs);    \
      if (SA1) STG_A(((KT) + 1) & 1, 1, (KT) + 1);                             \
      asm volatile("s_waitcnt lgkmcnt(0)" ::: "memory");                       \
      __builtin_amdgcn_s_setprio(1);                                           \
      _Pragma("unroll") for (int q = 0; q < 4; ++q)                            \
        _Pragma("unroll") for (int ni = 0; ni < 4; ++ni)                       \
          acc[2 * q][ni] = __builtin_amdgcn_mfma_f32_16x16x32_bf16(            \
              a[q], b0[ni], acc[2 * q][ni], 0, 0, 0);                          \
      __builtin_amdgcn_s_setprio(0);                                           \
      __builtin_amdgcn_s_barrier();                                            \
    }                                                                          \
    { /* p1: B(ks1)+A-even(ks1) */                                             \
      const int cs = (64 + lg * 16) ^ rswz;                                    \
      bf16x8 a[4];                                                             \
      _Pragma("unroll") for (int ni = 0; ni < 4; ++ni)                         \
        b1[ni] = *(const bf16x8*)(Bb + bro + ni * 2048 + cs);                  \
      _Pragma("unroll") for (int q = 0; q < 4; ++q)                            \
        a[q] = *(const bf16x8*)(Ab + ((wm * 4 + q) * 16 + l15) * 128 + cs);    \
      asm volatile("s_waitcnt lgkmcnt(0)" ::: "memory");                       \
      __builtin_amdgcn_s_setprio(1);                                           \
      _Pragma("unroll") for (int q = 0; q < 4; ++q)                            \
        _Pragma("unroll") for (int ni = 0; ni < 4; ++ni)                       \
          acc[2 * q][ni] = __builtin_amdgcn_mfma_f32_16x16x32_bf16(            \
              a[q], b1[ni], acc[2 * q][ni], 0, 0, 0);                          \
      __builtin_amdgcn_s_setprio(0);                                           \
      W1;                                                                      \
      __builtin_amdgcn_s_barrier();                                            \
    }                                                                          \
    { /* p2: A-odd(ks0); stage B01(KT+2) */                                    \
      const int cs = (lg * 16) ^ rswz;                                         \
      bf16x8 a[4];                                                             \
      _Pragma("unroll") for (int q = 0; q < 4; ++q)                            \
        a[q] = *(const bf16x8*)(Ab + 16384 + ((wm * 4 + q) * 16 + l15) * 128 + cs); \
      if (SB) { STG_B((KT) & 1, 0, (KT) + 2); STG_B((KT) & 1, 1, (KT) + 2); }  \
      asm volatile("s_waitcnt lgkmcnt(0)" ::: "memory");                       \
      __builtin_amdgcn_s_setprio(1);                                           \
      _Pragma("unroll") for (int q = 0; q < 4; ++q)                            \
        _Pragma("unroll") for (int ni = 0; ni < 4; ++ni)                       \
          acc[2 * q + 1][ni] = __builtin_amdgcn_mfma_f32_16x16x32_bf16(        \
              a[q], b0[ni], acc[2 * q + 1][ni], 0, 0, 0);                      \
      __builtin_amdgcn_s_setprio(0);                                           \
      __builtin_amdgcn_s_barrier();                                            \
    }                                                                          \
    { /* p3: A-odd(ks1); stage Ah0(KT+2) */                                    \
      const int cs = (64 + lg * 16) ^ rswz;                                    \
      bf16x8 a[4];                                                             \
      _Pragma("unroll") for (int q = 0; q < 4; ++q)                            \
        a[q] = *(const bf16x8*)(Ab + 16384 + ((wm * 4 + q) * 16 + l15) * 128 + cs); \
      if (SA0) STG_A((KT) & 1, 0, (KT) + 2);                                   \
      asm volatile("s_waitcnt lgkmcnt(0)" ::: "memory");                       \
      __builtin_amdgcn_s_setprio(1);                                           \
      _Pragma("unroll") for (int q = 0; q < 4; ++q)                            \
        _Pragma("unroll") for (int ni = 0; ni < 4; ++ni)                       \
          acc[2 * q + 1][ni] = __builtin_amdgcn_mfma_f32_16x16x32_bf16(        \
              a[q], b1[ni], acc[2 * q + 1][ni], 0, 0, 0);                      \
      __builtin_amdgcn_s_setprio(0);                                           \
      W3;                                                                      \
      __builtin_amdgcn_s_barrier();                                            \
    }                                                                          \
  }

  for (int kt = 0; kt < 14; ++kt) TILE_STEP(kt, 1, 1, 1, WV8, WV8);
  TILE_STEP(14, 1, 0, 0, WV8, WV2);
  TILE_STEP(15, 0, 0, 0, WV0, WNONE);

#undef TILE_STEP
#undef STG_A
#undef STG_B
}

// chunk-XOR for the epilogue transpose: 16B chunk c -> c ^ (c>>3), bijective.
__device__ __forceinline__ int xchunk4(int colf) {
  int c = colf >> 2;
  return ((c ^ (c >> 3)) << 2) | (colf & 3);
}

// ---------------------------------------------------------------------------
// Phase 1: [K|Q] = x @ Wkqv[h][:, :2048] + b for 8 heads. 256^2 core.
// ---------------------------------------------------------------------------
__global__ __launch_bounds__(512)
void kqv256(const bf16_t* __restrict__ xb, const bf16_t* __restrict__ Wt,
            const float* __restrict__ bkqv, int h0,
            bf16_t* __restrict__ Kc, bf16_t* __restrict__ Qc) {
  __shared__ bf16_t lds[65536];
  const int bid = blockIdx.x;
  const int lid = (bid & 7) * 128 + (bid >> 3);
  const int mb = lid & 15, nb = (lid >> 4) & 7, hz = lid >> 7;

  f32x4 acc[8][4] = {};
  mm256_core(xb + (size_t)mb * 256 * D_,
             Wt + ((size_t)hz * 2048 + (size_t)nb * 256) * D_, lds, acc);

  const int t = threadIdx.x;
  const int w = t >> 6, l = t & 63, l15 = l & 15, lg = l >> 4;
  const int wm = w >> 2, wn = w & 3;
  const int h = h0 + hz;

  float bias[4];
  #pragma unroll
  for (int ni = 0; ni < 4; ++ni)
    bias[ni] = bkqv[h * E_ + nb * 256 + wn * 64 + ni * 16 + l15];
  #pragma unroll
  for (int mi = 0; mi < 8; ++mi)
    #pragma unroll
    for (int ni = 0; ni < 4; ++ni)
      #pragma unroll
      for (int r = 0; r < 4; ++r) acc[mi][ni][r] += bias[ni];

  float* Ct = (float*)lds;   // [64][258], cols chunk-XOR swizzled
  const int cpair = t & 31;
  const int p0 = xchunk4(cpair * 8);
  const int p1 = xchunk4(cpair * 8 + 4);
  #pragma unroll
  for (int s = 0; s < 4; ++s) {
    __syncthreads();
    #pragma unroll
    for (int m2 = 0; m2 < 2; ++m2)
      #pragma unroll
      for (int ni = 0; ni < 4; ++ni)
        #pragma unroll
        for (int r = 0; r < 4; ++r)
          Ct[(wm * 32 + m2 * 16 + lg * 4 + r) * 258 +
             xchunk4(wn * 64 + ni * 16 + l15)] = acc[2 * s + m2][ni][r];
    __syncthreads();
    #pragma unroll
    for (int it = 0; it < 4; ++it) {
      int row64 = (t >> 5) + it * 16;
      int wmq = row64 >> 5, m2q = (row64 >> 4) & 1, r16 = row64 & 15;
      int c8 = cpair * 8;
      const float* r0 = &Ct[row64 * 258 + p0];
      const float* r1 = &Ct[row64 * 258 + p1];
      bf16x8 o = {(bf16_t)r0[0], (bf16_t)r0[1], (bf16_t)r0[2], (bf16_t)r0[3],
                  (bf16_t)r1[0], (bf16_t)r1[1], (bf16_t)r1[2], (bf16_t)r1[3]};
      int grow = mb * 256 + wmq * 128 + (2 * s + m2q) * 16 + r16;
      int b = grow >> 10, n = grow & (N_ - 1);
      int bhl = b * 8 + hz;
      size_t base = ((size_t)bhl * N_ + n) * D_;
      if (nb < 4)
        *(bf16x8*)(Kc + base + nb * 256 + c8) = o;
      else
        *(bf16x8*)(Qc + base + nb * 256 - 1024 + c8) = o;
    }
  }
}

// ---------------------------------------------------------------------------
// Phase 2a: S = scale * Q.K^T, lower-triangle 256x256 tiles (10 per bh).
// ---------------------------------------------------------------------------
__global__ __launch_bounds__(512)
void s_gemm256(const bf16_t* __restrict__ Qc, const bf16_t* __restrict__ Kc,
               float* __restrict__ SgC) {
  __shared__ bf16_t lds[65536];
  const int bid = blockIdx.x;
  const int lid = (bid & 7) * 40 + (bid >> 3);
  const int idx = lid % 10;
  const int bhl = lid / 10;
  int qt = 0;
  while ((qt + 1) * (qt + 2) / 2 <= idx) ++qt;
  const int kt = idx - qt * (qt + 1) / 2;

  f32x4 acc[8][4] = {};
  mm256_core(Qc + ((size_t)bhl * N_ + (size_t)qt * 256) * D_,
             Kc + ((size_t)bhl * N_ + (size_t)kt * 256) * D_, lds, acc);

  const int t = threadIdx.x;
  const int w = t >> 6, l = t & 63, l15 = l & 15, lg = l >> 4;
  const int wm = w >> 2, wn = w & 3;
  const float SCALE = 0.045084220027780106f;   // log2(e)/sqrt(1024)
  float* So = SgC + (((size_t)bhl * 10 + idx) << 16);

  #pragma unroll
  for (int mi = 0; mi < 8; ++mi)
    #pragma unroll
    for (int ni = 0; ni < 4; ++ni)
      #pragma unroll
      for (int r = 0; r < 4; ++r) {
        int rl = wm * 128 + mi * 16 + lg * 4 + r;
        int cl = wn * 64 + ni * 16 + l15;
        float z = acc[mi][ni][r] * SCALE;
        if (kt * 256 + cl > qt * 256 + rl) z = -1e30f;
        acc[mi][ni][r] = z;
      }

  float* Ct = (float*)lds;
  const int cpair = t & 31;
  const int p0 = xchunk4(cpair * 8);
  const int p1 = xchunk4(cpair * 8 + 4);
  #pragma unroll
  for (int s = 0; s < 4; ++s) {
    __syncthreads();
    #pragma unroll
    for (int m2 = 0; m2 < 2; ++m2)
      #pragma unroll
      for (int ni = 0; ni < 4; ++ni)
        #pragma unroll
        for (int r = 0; r < 4; ++r)
          Ct[(wm * 32 + m2 * 16 + lg * 4 + r) * 258 +
             xchunk4(wn * 64 + ni * 16 + l15)] = acc[2 * s + m2][ni][r];
    __syncthreads();
    #pragma unroll
    for (int it = 0; it < 4; ++it) {
      int row64 = (t >> 5) + it * 16;
      int wmq = row64 >> 5, m2q = (row64 >> 4) & 1, r16 = row64 & 15;
      int c8 = cpair * 8;
      const float* r0 = &Ct[row64 * 258 + p0];
      const float* r1 = &Ct[row64 * 258 + p1];
      float4 v0 = {r0[0], r0[1], r0[2], r0[3]};
      float4 v1 = {r1[0], r1[1], r1[2], r1[3]};
      int rl = wmq * 128 + (2 * s + m2q) * 16 + r16;
      *(float4*)(So + (size_t)rl * 256 + c8) = v0;
      *(float4*)(So + (size_t)rl * 256 + c8 + 4) = v1;
    }
  }
}

// ---------------------------------------------------------------------------
// V gemm (unchanged)
// ---------------------------------------------------------------------------
__global__ __launch_bounds__(256)
void v_gemm(const bf16_t* __restrict__ xb, const bf16_t* __restrict__ Wvt,
            const float* __restrict__ bkqv, bf16_t* __restrict__ Vt) {
  const int nt = blockIdx.x;
  const int h = blockIdx.y;
  const int t = threadIdx.x;
  const int w = t >> 6, l = t & 63, l15 = l & 15, lg = l >> 4;

  __shared__ bf16_t As2[64 * 64];
  __shared__ bf16_t Bs2[128 * 64];
  const bf16_t* Wvh = Wvt + (size_t)h * DH_ * D_;
  const bf16_t* Bn = xb + (size_t)nt * 128 * D_;

  f32x4 acc[4][2] = {};
  const int rswz = (l15 & 7) << 4;

  for (int kb = 0; kb < 16; ++kb) {
    __syncthreads();
    #pragma unroll
    for (int i = 0; i < 2; ++i) {
      int idx = t + i * 256;
      int row = idx >> 3, c = idx & 7;
      gload_lds16(Wvh + (size_t)row * D_ + kb * 64 + ((c ^ (row & 7)) << 3),
                  (char*)As2 + idx * 16);
    }
    #pragma unroll
    for (int i = 0; i < 4; ++i) {
      int idx = t + i * 256;
      int row = idx >> 3, c = idx & 7;
      gload_lds16(Bn + (size_t)row * D_ + kb * 64 + ((c ^ (row & 7)) << 3),
                  (char*)Bs2 + idx * 16);
    }
    __syncthreads();
    #pragma unroll
    for (int ks = 0; ks < 2; ++ks) {
      const int cswz = (ks * 64 + lg * 16) ^ rswz;
      bf16x8 a[4], b[2];
      #pragma unroll
      for (int mi = 0; mi < 4; ++mi)
        a[mi] = *(const bf16x8*)((const char*)As2 + (mi * 16 + l15) * 128 + cswz);
      #pragma unroll
      for (int ni = 0; ni < 2; ++ni)
        b[ni] = *(const bf16x8*)((const char*)Bs2 + (w * 32 + ni * 16 + l15) * 128 + cswz);
      #pragma unroll
      for (int mi = 0; mi < 4; ++mi)
        #pragma unroll
        for (int ni = 0; ni < 2; ++ni)
          acc[mi][ni] = __builtin_amdgcn_mfma_f32_16x16x32_bf16(a[mi], b[ni], acc[mi][ni], 0, 0, 0);
    }
  }

  #pragma unroll
  for (int mi = 0; mi < 4; ++mi)
    #pragma unroll
    for (int r = 0; r < 4; ++r) {
      int dh = mi * 16 + lg * 4 + r;
      float bias = bkqv[h * E_ + 2048 + dh];
      #pragma unroll
      for (int ni = 0; ni < 2; ++ni) {
        int nn = nt * 128 + w * 32 + ni * 16 + l15;
        int b = nn >> 10, n = nn & (N_ - 1);
        int bh = b * H_ + h;
        Vt[((size_t)bh * DH_ + dh) * N_ + n] = (bf16_t)(acc[mi][ni][r] + bias);
      }
    }
}

// ---------------------------------------------------------------------------
// Phase 2b: softmax + P.V (unchanged)
// ---------------------------------------------------------------------------
__global__ __launch_bounds__(256)
void softmax_pv(const float* __restrict__ SgC, const bf16_t* __restrict__ Vt,
                bf16_t* __restrict__ sa, int c) {
  const int qt = blockIdx.x;
  const int bhl = blockIdx.y;
  const int t = threadIdx.x;
  const int w = t >> 6, l = t & 63, l15 = l & 15, lg = l >> 4;
  const int b = bhl >> 3, h = c * 8 + (bhl & 7);
  const int bh = b * H_ + h;

  const int qrow = qt * 64 + w * 16 + l15;
  const int qt8 = qt >> 2;
  const float* Sbh = SgC + (((size_t)bhl * 10) << 16);
  const bf16_t* Vh = Vt + (size_t)bh * DH_ * N_;

  f32x4 accO[4] = {};
  float m = -1e30f, lsum = 0.f;

  for (int j = 0; j <= qt; ++j) {
    const int jb = j * 64;
    const int tid = qt8 * (qt8 + 1) / 2 + (j >> 2);
    const float* Srow = Sbh + ((size_t)tid << 16) + (size_t)(qrow & 255) * 256 + (jb & 255);

    float4 sA = *(const float4*)(Srow + lg * 8);
    float4 sB = *(const float4*)(Srow + lg * 8 + 4);
    float4 sC = *(const float4*)(Srow + 32 + lg * 8);
    float4 sD = *(const float4*)(Srow + 32 + lg * 8 + 4);

    float zm = fmaxf(fmaxf(fmaxf(sA.x, sA.y), fmaxf(sA.z, sA.w)),
                     fmaxf(fmaxf(sB.x, sB.y), fmaxf(sB.z, sB.w)));
    zm = fmaxf(zm, fmaxf(fmaxf(fmaxf(sC.x, sC.y), fmaxf(sC.z, sC.w)),
                         fmaxf(fmaxf(sD.x, sD.y), fmaxf(sD.z, sD.w))));
    zm = fmaxf(zm, __shfl_xor(zm, 16));
    zm = fmaxf(zm, __shfl_xor(zm, 32));

    float mnew = fmaxf(m, zm);
    float scl = exp2f(m - mnew);
    m = mnew;

    float p[16];
    p[0] = exp2f(sA.x - mnew); p[1] = exp2f(sA.y - mnew);
    p[2] = exp2f(sA.z - mnew); p[3] = exp2f(sA.w - mnew);
    p[4] = exp2f(sB.x - mnew); p[5] = exp2f(sB.y - mnew);
    p[6] = exp2f(sB.z - mnew); p[7] = exp2f(sB.w - mnew);
    p[8] = exp2f(sC.x - mnew); p[9] = exp2f(sC.y - mnew);
    p[10] = exp2f(sC.z - mnew); p[11] = exp2f(sC.w - mnew);
    p[12] = exp2f(sD.x - mnew); p[13] = exp2f(sD.y - mnew);
    p[14] = exp2f(sD.z - mnew); p[15] = exp2f(sD.w - mnew);

    float rs = 0.f;
    #pragma unroll
    for (int i = 0; i < 16; ++i) rs += p[i];
    rs += __shfl_xor(rs, 16);
    rs += __shfl_xor(rs, 32);
    lsum = lsum * scl + rs;

    float sclO[4];
    #pragma unroll
    for (int r = 0; r < 4; ++r) sclO[r] = __shfl(scl, lg * 4 + r);
    #pragma unroll
    for (int db = 0; db < 4; ++db)
      #pragma unroll
      for (int r = 0; r < 4; ++r) accO[db][r] *= sclO[r];

    bf16x8 pa0 = {(bf16_t)p[0], (bf16_t)p[1], (bf16_t)p[2], (bf16_t)p[3],
                  (bf16_t)p[4], (bf16_t)p[5], (bf16_t)p[6], (bf16_t)p[7]};
    bf16x8 pa1 = {(bf16_t)p[8], (bf16_t)p[9], (bf16_t)p[10], (bf16_t)p[11],
                  (bf16_t)p[12], (bf16_t)p[13], (bf16_t)p[14], (bf16_t)p[15]};

    #pragma unroll
    for (int db = 0; db < 4; ++db) {
      const bf16_t* vp = Vh + (size_t)(db * 16 + l15) * N_ + jb;
      bf16x8 vb0 = *(const bf16x8*)(vp + lg * 8);
      bf16x8 vb1 = *(const bf16x8*)(vp + 32 + lg * 8);
      accO[db] = __builtin_amdgcn_mfma_f32_16x16x32_bf16(pa0, vb0, accO[db], 0, 0, 0);
      accO[db] = __builtin_amdgcn_mfma_f32_16x16x32_bf16(pa1, vb1, accO[db], 0, 0, 0);
    }
  }

  float lO[4];
  #pragma unroll
  for (int r = 0; r < 4; ++r) lO[r] = __shfl(lsum, lg * 4 + r);

  #pragma unroll
  for (int db = 0; db < 4; ++db)
    #pragma unroll
    for (int r = 0; r < 4; ++r) {
      int row = qt * 64 + w * 16 + lg * 4 + r;
      int col = h * DH_ + db * 16 + l15;
      sa[((size_t)b * N_ + row) * D_ + col] = (bf16_t)(accO[db][r] / lO[r]);
    }
}

// ---------------------------------------------------------------------------
// Phase 3: out = sa @ Wp + bp (m97 128^2 structure, fp32 out)
// ---------------------------------------------------------------------------
__global__ __launch_bounds__(256)
void out_gemm(const bf16_t* __restrict__ A, const bf16_t* __restrict__ Bt,
              const float* __restrict__ bp, float* __restrict__ out) {
  const int mb = blockIdx.x, nb = blockIdx.y;
  const int t = threadIdx.x;
  const int w = t >> 6, l = t & 63, l15 = l & 15, lg = l >> 4;
  const int wr = (w >> 1) * 64, wc = (w & 1) * 64;

  __shared__ bf16_t As[128 * 64];
  __shared__ bf16_t Bs[128 * 64];

  const int srow = w * 32 + (l >> 3);
  const int scol = (l & 7) * 8;
  const bf16_t* ag = A + (size_t)(mb * 128 + srow) * D_ + scol;
  const bf16_t* bg = Bt + (size_t)(nb * 128 + srow) * D_ + scol;
  char* asl = (char*)As + w * 4096;
  char* bsl = (char*)Bs + w * 4096;

  f32x4 acc[4][4] = {};

  for (int kb = 0; kb < 16; ++kb) {
    __syncthreads();
    #pragma unroll
    for (int i = 0; i < 4; ++i) {
      gload_lds16(ag + (size_t)i * 8 * D_ + kb * 64, asl + i * 1024);
      gload_lds16(bg + (size_t)i * 8 * D_ + kb * 64, bsl + i * 1024);
    }
    __syncthreads();
    #pragma unroll
    for (int ks = 0; ks < 2; ++ks) {
      bf16x8 a[4], b[4];
      #pragma unroll
      for (int mi = 0; mi < 4; ++mi)
        a[mi] = *(const bf16x8*)((const char*)As + (wr + mi * 16 + l15) * 128 + ks * 64 + lg * 16);
      #pragma unroll
      for (int ni = 0; ni < 4; ++ni)
        b[ni] = *(const bf16x8*)((const char*)Bs + (wc + ni * 16 + l15) * 128 + ks * 64 + lg * 16);
      #pragma unroll
      for (int mi = 0; mi < 4; ++mi)
        #pragma unroll
        for (int ni = 0; ni < 4; ++ni)
          acc[mi][ni] = __builtin_amdgcn_mfma_f32_16x16x32_bf16(a[mi], b[ni], acc[mi][ni], 0, 0, 0);
    }
  }

  #pragma unroll
  for (int ni = 0; ni < 4; ++ni) {
    int e = nb * 128 + wc + ni * 16 + l15;
    float bias = bp[e];
    #pragma unroll
    for (int mi = 0; mi < 4; ++mi)
      #pragma unroll
      for (int r = 0; r < 4; ++r) {
        int grow = mb * 128 + wr + mi * 16 + lg * 4 + r;
        out[(size_t)grow * D_ + e] = acc[mi][ni][r] + bias;
      }
  }
}

// ---------------------------------------------------------------------------
extern "C" void kernel_launch(void* const* d_in, const int* in_sizes, int n_in,
                              void* d_out, int out_size, void* d_ws, size_t ws_size,
                              hipStream_t stream) {
  const float* x    = (const float*)d_in[0];
  const float* Wkqv = (const float*)d_in[1];
  const float* bkqv = (const float*)d_in[2];
  const float* Wp   = (const float*)d_in[3];
  const float* bp   = (const float*)d_in[4];
  float* out = (float*)d_out;
  char* ws = (char*)d_ws;

  const size_t MB = 1 << 20;
  bf16_t* xb  = (bf16_t*)(ws);             //   8 MiB
  bf16_t* sa  = (bf16_t*)(ws + 8 * MB);    //   8 MiB
  bf16_t* Wpt = (bf16_t*)(ws + 16 * MB);   //   2 MiB
  bf16_t* Vt  = (bf16_t*)(ws + 18 * MB);   //   8 MiB
  bf16_t* Qc  = (bf16_t*)(ws + 26 * MB);   //  64 MiB (32 bh)
  bf16_t* Kc  = (bf16_t*)(ws + 90 * MB);   //  64 MiB (32 bh)
  bf16_t* Wt  = (bf16_t*)(ws + 154 * MB);  //  32 MiB (8 heads)
  bf16_t* Wvt = (bf16_t*)(ws + 186 * MB);  //   2 MiB
  float*  SgC = (float*) (ws + 188 * MB);  //  80 MiB
  // total 268 MiB (< proven-safe 285,212,672 B)

  hipLaunchKernelGGL(conv_x, dim3(1024), dim3(256), 0, stream, x, xb);
  hipLaunchKernelGGL(conv_wp, dim3(32, 32), dim3(256), 0, stream, Wp, Wpt);
  hipLaunchKernelGGL(conv_wv, dim3(2, 32, 16), dim3(256), 0, stream, Wkqv, Wvt);
  hipLaunchKernelGGL(v_gemm, dim3(32, 16), dim3(256), 0, stream, xb, Wvt, bkqv, Vt);

  for (int c = 0; c < 2; ++c) {
    hipLaunchKernelGGL(conv_wkqv, dim3(32, 16, 8), dim3(256), 0, stream,
                       Wkqv, Wt, c * 8);
    hipLaunchKernelGGL(kqv256, dim3(1024), dim3(512), 0, stream,
                       xb, Wt, bkqv, c * 8, Kc, Qc);
    hipLaunchKernelGGL(s_gemm256, dim3(320), dim3(512), 0, stream,
                       Qc, Kc, SgC);
    hipLaunchKernelGGL(softmax_pv, dim3(16, 32), dim3(256), 0, stream,
                       SgC, Vt, sa, c);
  }

  hipLaunchKernelGGL(out_gemm, dim3(32, 8), dim3(256), 0, stream, sa, Wpt, bp, out);
}